// Round 8
// baseline (613.032 us; speedup 1.0000x reference)
//
#include <hip/hip_runtime.h>
#include <hip/hip_cooperative_groups.h>
#include <math.h>

namespace cg = cooperative_groups;

#define SEQ   1024
#define EMB   1024
#define MN    16

typedef _Float16 f16;
typedef __attribute__((ext_vector_type(4))) _Float16 f16x4;
typedef __attribute__((ext_vector_type(8))) _Float16 f16x8;
typedef __attribute__((ext_vector_type(4))) float f32x4;

struct Params {
  const float *k, *q, *v, *Wq, *bq, *Wk, *Wv, *Wp, *bp, *aw, *gamma, *beta;
  float *out;
  float *uq, *uk, *cq, *sq, *sk, *nodes, *Wn;
  f16 *WvTh, *vTh, *wh, *Ph, *csh, *csl, *Hsh, *Hsl;
  int NB;
};

__global__ __launch_bounds__(256, 4) void mega_kernel(Params P)
{
  __shared__ __align__(16) char SMEM[36864];   // 36KB -> 4 blocks/CU (4*36864=147456 <= 160KB)
  cg::grid_group grid = cg::this_grid();
  const int bid = blockIdx.x, tid = threadIdx.x;
  const int NB = P.NB;

  // ================= Phase 1: fold + ztrans (v,Wv -> f16 T) + cq + Wn zero =================
  for (int t = bid; t < 1410; t += NB) {
    __syncthreads();
    if (t < 128) {
      int idx = t*256 + tid;
      bool isQ = idx < 16384;
      int li = isQ ? idx : idx - 16384;          // li = e*16 + n
      int e = li >> 4, n = li & 15;
      const float* W = isQ ? P.Wq : P.Wk;
      const float* w = isQ ? P.aw : P.aw + 64;
      const float* wp = &W[(size_t)e*EMB + n*64];
      float s = 0.f;
      #pragma unroll 16
      for (int d = 0; d < 64; ++d) s = fmaf(wp[d], w[d], s);
      (isQ ? P.uq : P.uk)[li] = s;
    } else if (t < 1408) {
      int tt = t - 128;
      int z = tt >> 8;                            // 0..4 (4 v batches + Wv)
      int ty = (tt >> 4) & 15, tx = tt & 15;
      float (*tile)[65] = (float(*)[65])SMEM;     // 16.6KB
      int r0 = ty*64, c0 = tx*64;
      const float* src = (z < 4) ? &P.v[(size_t)(z*SEQ + r0)*EMB + c0]
                                 : &P.Wv[(size_t)r0*EMB + c0];
      int rr = tid >> 4, c4 = (tid & 15)*4;
      #pragma unroll
      for (int i = 0; i < 4; ++i) {
        int row = rr + i*16;
        float4 wv = *reinterpret_cast<const float4*>(&src[(size_t)row*EMB + c4]);
        tile[row][c4] = wv.x; tile[row][c4+1] = wv.y;
        tile[row][c4+2] = wv.z; tile[row][c4+3] = wv.w;
      }
      __syncthreads();
      #pragma unroll
      for (int i = 0; i < 4; ++i) {
        int cc = rr + i*16;
        f16x4 hh;
        #pragma unroll
        for (int jj = 0; jj < 4; ++jj) hh[jj] = (f16)tile[c4+jj][cc];
        size_t o = (z < 4) ? ((size_t)(z*EMB + c0 + cc))*SEQ + r0 + c4
                           : ((size_t)(c0 + cc))*EMB + r0 + c4;
        *reinterpret_cast<f16x4*>(&((z < 4) ? P.vTh : P.WvTh)[o]) = hh;
      }
    } else if (t == 1408) {
      if (tid < 16) {
        float s = 0.f;
        for (int d = 0; d < 64; ++d) s = fmaf(P.bq[tid*64+d], P.aw[d], s);
        P.cq[tid] = s;
      }
    } else {
      for (int u = tid; u < 1024; u += 256) P.Wn[u] = 0.f;
    }
  }
  grid.sync();

  // ================= Phase 2: sqsk (8 rows per task; LDS union rowbuf->part) =================
  for (int t = bid; t < 1024; t += NB) {
    bool isQ = t < 512;
    int row0 = (isQ ? t : t - 512)*8;
    const float* X = isQ ? P.q : P.k;
    const float* U = isQ ? P.uq : P.uk;
    float (*rowbuf)[1024] = (float(*)[1024])SMEM;          // 32KB
    __syncthreads();
    #pragma unroll
    for (int p = 0; p < 8; ++p) {
      int fi = p*256 + tid;
      int r = fi >> 8, c4 = (fi & 255)*4;
      *reinterpret_cast<float4*>(&rowbuf[r][c4]) =
          *reinterpret_cast<const float4*>(&X[(size_t)(row0+r)*EMB + c4]);
    }
    __syncthreads();
    int n = tid & 15, ch = tid >> 4;
    float acc[8] = {0,0,0,0,0,0,0,0};
    #pragma unroll 4
    for (int e0 = 0; e0 < 64; ++e0) {
      int e = ch*64 + e0;
      float u = U[e*16 + n];
      #pragma unroll
      for (int r = 0; r < 8; ++r) acc[r] = fmaf(rowbuf[r][e], u, acc[r]);
    }
    __syncthreads();                                        // rowbuf consumed
    float (*part)[8][17] = (float(*)[8][17])SMEM;           // 8.7KB (aliases rowbuf)
    #pragma unroll
    for (int r = 0; r < 8; ++r) part[ch][r][n] = acc[r];
    __syncthreads();
    if (tid < 128) {
      int r = tid >> 4, nn = tid & 15;
      float s = isQ ? P.cq[nn] : 0.f;
      #pragma unroll
      for (int c = 0; c < 16; ++c) s += part[c][r][nn];
      (isQ ? P.sq : P.sk)[(size_t)(row0+r)*16 + nn] = s;
    }
  }
  grid.sync();

  // ================= Phase 3: Chebyshev nodes per (b,n) =================
  for (int t = bid; t < 64; t += NB) {
    int b = t >> 4, n = t & 15;
    float mn = 1e30f, mx = -1e30f;
    #pragma unroll
    for (int s = 0; s < 4; ++s) {
      float vv = P.sq[((size_t)(b*SEQ + tid + s*256))*16 + n];
      mn = fminf(mn, vv); mx = fmaxf(mx, vv);
    }
    float* smn = (float*)SMEM;
    float* smx = smn + 256;
    __syncthreads();
    smn[tid] = mn; smx[tid] = mx;
    __syncthreads();
    for (int off = 128; off > 0; off >>= 1) {
      if (tid < off) { smn[tid] = fminf(smn[tid], smn[tid+off]);
                       smx[tid] = fmaxf(smx[tid], smx[tid+off]); }
      __syncthreads();
    }
    if (tid < MN) {
      float c = 0.5f*(smn[0]+smx[0]);
      float r = fmaxf(0.5f*(smx[0]-smn[0]), 1e-4f);
      P.nodes[t*MN + tid] = c + r*cosf(tid*(3.14159265358979323f/(MN-1)));
    }
  }
  grid.sync();

  // ================= Phase 4: wmat (exp(tanh)) + Wn row-sums =================
  for (int t = bid; t < 1024; t += NB) {
    int b = t >> 8, n = (t >> 4) & 15, qd = t & 15;
    int j0 = qd*64;
    float* nodesh = (float*)SMEM;
    __syncthreads();
    if (tid < MN) nodesh[tid] = P.nodes[(b*16+n)*MN + tid];
    __syncthreads();
    int jl = tid & 63, mg = tid >> 6;
    int j = j0 + jl;
    float skv = P.sk[((size_t)(b*SEQ + j))*16 + n];
    #pragma unroll
    for (int mm = 0; mm < 4; ++mm) {
      int m = mg*4 + mm;
      float s = nodesh[m] + skv;
      float e2 = __expf(2.f*s);
      float th = 1.f - 2.f/(e2+1.f);
      float w = __expf(th);
      P.wh[(size_t)(b*256 + n*MN + m)*1024 + j] = (f16)w;
      float ws = w;
      #pragma unroll
      for (int off = 32; off > 0; off >>= 1) ws += __shfl_xor(ws, off);
      if (jl == 0) atomicAdd(&P.Wn[(b*16+n)*MN + m], ws);
    }
  }
  grid.sync();

  // ================= Phase 5: gemm1 (tasks 0..255) || coeff (tasks 256..511) =================
  for (int t = bid; t < 512; t += NB) {
    __syncthreads();
    if (t < 256) {
      // P = wh @ vT^T', 64x64 tile, K=1024, plain f16, LDS 16KB
      int swz = (t & 7)*32 + (t >> 3);
      int bx = swz & 15, by = swz >> 4;
      int z = by >> 2;
      int grow = by*64, bcol = bx*64;
      int wid = tid >> 6, lane = tid & 63;
      int wm = wid >> 1, wn = wid & 1;
      int asel = lane >> 4, l15 = lane & 15;
      const f16* Bz = P.vTh + (size_t)z*EMB*SEQ;
      char* lds = SMEM;
      f32x4 acc[2][2];
      #pragma unroll
      for (int i = 0; i < 2; ++i)
        #pragma unroll
        for (int jx = 0; jx < 2; ++jx)
          acc[i][jx] = (f32x4){0.f,0.f,0.f,0.f};
      for (int kt = 0; kt < 16; ++kt) {
        const int k0 = kt*64;
        __syncthreads();
        #pragma unroll
        for (int r = 0; r < 4; ++r) {
          int ci = ((r & 1) << 8) + tid;
          int row = ci >> 3, kc = ci & 7;
          int kcg = kc ^ (row & 7);
          const f16* base = (r < 2) ? P.wh : Bz;
          size_t roff = (r < 2) ? (size_t)(grow + row) : (size_t)(bcol + row);
          const char* src = (const char*)(base + roff*1024 + k0 + kcg*8);
          char* dst = lds + (r*256 + wid*64)*16;
          __builtin_amdgcn_global_load_lds(
              (const __attribute__((address_space(1))) unsigned int*)src,
              (__attribute__((address_space(3))) unsigned int*)dst, 16, 0, 0);
        }
        __syncthreads();
        #pragma unroll
        for (int kk = 0; kk < 2; ++kk) {
          f16x8 afh[2], bfh[2];
          #pragma unroll
          for (int mf = 0; mf < 2; ++mf) {
            int row = wm*32 + mf*16 + l15;
            int kcx = (kk*4 + asel) ^ (row & 7);
            afh[mf] = *reinterpret_cast<const f16x8*>(lds + row*128 + kcx*16);
          }
          #pragma unroll
          for (int nf = 0; nf < 2; ++nf) {
            int col = wn*32 + nf*16 + l15;
            int kcx = (kk*4 + asel) ^ (col & 7);
            bfh[nf] = *reinterpret_cast<const f16x8*>(lds + 8192 + col*128 + kcx*16);
          }
          #pragma unroll
          for (int mf = 0; mf < 2; ++mf)
            #pragma unroll
            for (int nf = 0; nf < 2; ++nf)
              acc[mf][nf] = __builtin_amdgcn_mfma_f32_16x16x32_f16(afh[mf], bfh[nf], acc[mf][nf], 0, 0, 0);
        }
      }
      const int crow0 = grow + wm*32 + asel*4;
      const int ccol0 = bcol + wn*32 + l15;
      #pragma unroll
      for (int nf = 0; nf < 2; ++nf)
        #pragma unroll
        for (int mf = 0; mf < 2; ++mf)
          #pragma unroll
          for (int jx = 0; jx < 4; ++jx)
            P.Ph[(size_t)(crow0 + mf*16 + jx)*1024 + ccol0 + nf*16] = (f16)acc[mf][nf][jx];
    } else {
      // coeff: cs = 1024 * normalized barycentric coeffs, f16 split
      int tc = t - 256;
      int ic = tc & 63, b = tc >> 6;
      float (*nsh)[MN] = (float(*)[MN])SMEM;                  // 16x16
      float (*wsh)[MN] = ((float(*)[MN])SMEM) + 16;
      {
        int nn = tid >> 4, mm = tid & 15;
        nsh[nn][mm] = P.nodes[(b*16+nn)*MN + mm];
        wsh[nn][mm] = P.Wn[(b*16+nn)*MN + mm];
      }
      __syncthreads();
      int il = tid >> 4, n = tid & 15;
      int i = ic*16 + il;
      float s = P.sq[((size_t)(b*SEQ + i))*16 + n];
      float lam[MN];
      float den = 0.f;
      int ex = -1;
      #pragma unroll
      for (int m = 0; m < MN; ++m) {
        float diff = s - nsh[n][m];
        float wb = ((m == 0) | (m == MN-1)) ? 0.5f : 1.0f;
        wb = (m & 1) ? -wb : wb;
        if (diff == 0.f) ex = m;
        lam[m] = wb / diff;
        den = fmaf(lam[m], wsh[n][m], den);
      }
      float rden = 1024.f / den;
      f16* hp = &P.csh[((size_t)(b*SEQ + i))*256 + n*MN];
      f16* lp = &P.csl[((size_t)(b*SEQ + i))*256 + n*MN];
      #pragma unroll
      for (int m8 = 0; m8 < 2; ++m8) {
        f16x8 hv, lv;
        #pragma unroll
        for (int jj = 0; jj < 8; ++jj) {
          int m = m8*8 + jj;
          float c = (ex >= 0) ? ((m == ex) ? 1024.f/wsh[n][ex] : 0.f) : lam[m]*rden;
          f16 h = (f16)c;
          hv[jj] = h; lv[jj] = (f16)(c - (float)h);
        }
        *reinterpret_cast<f16x8*>(&hp[m8*8]) = hv;
        *reinterpret_cast<f16x8*>(&lp[m8*8]) = lv;
      }
    }
  }
  grid.sync();

  // ================= Phase 6: ghprep (G via MFMA -> Hs = (G@Wp)*2^-10 split) =================
  for (int t = bid; t < 256; t += NB) {
    int oc = t & 3, n = (t >> 2) & 15, b = t >> 6;
    int bn = b*16 + n;
    float (*Gsh)[64] = (float(*)[64])SMEM;                    // 4KB
    int w = tid >> 6, lane = tid & 63;
    int l15 = lane & 15, asel = lane >> 4;
    __syncthreads();
    f32x4 acc = (f32x4){0.f,0.f,0.f,0.f};
    #pragma unroll 4
    for (int ks = 0; ks < 32; ++ks) {
      size_t bo = ((size_t)(n*64 + w*16 + l15))*1024 + ks*32 + asel*8;
      f16x8 bh = *reinterpret_cast<const f16x8*>(&P.WvTh[bo]);
      size_t ao = ((size_t)(bn*MN + l15))*1024 + ks*32 + asel*8;
      f16x8 ah = *reinterpret_cast<const f16x8*>(&P.Ph[ao]);
      acc = __builtin_amdgcn_mfma_f32_16x16x32_f16(ah, bh, acc, 0, 0, 0);
    }
    #pragma unroll
    for (int jx = 0; jx < 4; ++jx)
      Gsh[asel*4 + jx][w*16 + l15] = acc[jx];
    __syncthreads();
    int o = oc*256 + tid;
    float a2[MN];
    #pragma unroll
    for (int m = 0; m < MN; ++m) a2[m] = 0.f;
    for (int d = 0; d < 64; ++d) {
      float wp = P.Wp[(size_t)(n*64 + d)*1024 + o];
      #pragma unroll
      for (int m = 0; m < MN; ++m) a2[m] = fmaf(wp, Gsh[m][d], a2[m]);
    }
    f16 hbuf[MN], lbuf[MN];
    #pragma unroll
    for (int m = 0; m < MN; ++m) {
      float vv = a2[m] * (1.f/1024.f);
      f16 h = (f16)vv;
      hbuf[m] = h; lbuf[m] = (f16)(vv - (float)h);
    }
    size_t base = ((size_t)(b*1024 + o))*256 + n*MN;
    #pragma unroll
    for (int m8 = 0; m8 < 2; ++m8) {
      *reinterpret_cast<f16x8*>(&P.Hsh[base + m8*8]) = *reinterpret_cast<f16x8*>(&hbuf[m8*8]);
      *reinterpret_cast<f16x8*>(&P.Hsl[base + m8*8]) = *reinterpret_cast<f16x8*>(&lbuf[m8*8]);
    }
  }
  grid.sync();

  // ================= Phase 7: gemm2 split-3, 64x64 tiles, K=256, out = cs@Hs^T' + bp =================
  for (int t = bid; t < 1024; t += NB) {
    int swz = (t & 7)*128 + (t >> 3);             // bijective XCD swizzle
    int bx = swz & 15;                             // col tile
    int by = swz >> 4;                             // row tile 0..63
    int row0 = by*64;
    int bcol = bx*64;
    int z = by >> 4;
    const f16* Bzh = P.Hsh + (size_t)z*1024*256;
    const f16* Bzl = P.Hsl + (size_t)z*1024*256;
    int wid = tid >> 6, lane = tid & 63;
    int wm = wid >> 1, wn = wid & 1;
    int asel = lane >> 4, l15 = lane & 15;
    char* lds = SMEM;                              // 32KB staging
    f32x4 acc[2][2];
    #pragma unroll
    for (int i = 0; i < 2; ++i)
      #pragma unroll
      for (int jx = 0; jx < 2; ++jx)
        acc[i][jx] = (f32x4){0.f,0.f,0.f,0.f};
    for (int kt = 0; kt < 4; ++kt) {
      const int k0 = kt*64;
      __syncthreads();
      #pragma unroll
      for (int r = 0; r < 8; ++r) {
        int ci = ((r & 1) << 8) + tid;
        int row = ci >> 3, kc = ci & 7;
        int kcg = kc ^ (row & 7);
        const f16* base = (r < 2) ? P.csh : (r < 4) ? P.csl : (r < 6) ? Bzh : Bzl;
        size_t roff = (r < 4) ? (size_t)(row0 + row)*256 : (size_t)(bcol + row)*256;
        const char* src = (const char*)(base + roff + k0 + kcg*8);
        char* dst = lds + (r*256 + wid*64)*16;
        __builtin_amdgcn_global_load_lds(
            (const __attribute__((address_space(1))) unsigned int*)src,
            (__attribute__((address_space(3))) unsigned int*)dst, 16, 0, 0);
      }
      __syncthreads();
      #pragma unroll
      for (int kk = 0; kk < 2; ++kk) {
        f16x8 afh[2], afl[2], bfh[2], bfl[2];
        #pragma unroll
        for (int mf = 0; mf < 2; ++mf) {
          int row = wm*32 + mf*16 + l15;
          int kcx = (kk*4 + asel) ^ (row & 7);
          afh[mf] = *reinterpret_cast<const f16x8*>(lds + row*128 + kcx*16);
          afl[mf] = *reinterpret_cast<const f16x8*>(lds + 8192 + row*128 + kcx*16);
        }
        #pragma unroll
        for (int nf = 0; nf < 2; ++nf) {
          int col = wn*32 + nf*16 + l15;
          int kcx = (kk*4 + asel) ^ (col & 7);
          bfh[nf] = *reinterpret_cast<const f16x8*>(lds + 16384 + col*128 + kcx*16);
          bfl[nf] = *reinterpret_cast<const f16x8*>(lds + 24576 + col*128 + kcx*16);
        }
        #pragma unroll
        for (int mf = 0; mf < 2; ++mf)
          #pragma unroll
          for (int nf = 0; nf < 2; ++nf) {
            acc[mf][nf] = __builtin_amdgcn_mfma_f32_16x16x32_f16(afh[mf], bfh[nf], acc[mf][nf], 0, 0, 0);
            acc[mf][nf] = __builtin_amdgcn_mfma_f32_16x16x32_f16(afh[mf], bfl[nf], acc[mf][nf], 0, 0, 0);
            acc[mf][nf] = __builtin_amdgcn_mfma_f32_16x16x32_f16(afl[mf], bfh[nf], acc[mf][nf], 0, 0, 0);
          }
      }
    }
    const int crow0 = row0 + wm*32 + asel*4;
    const int ccol0 = bcol + wn*32 + l15;
    #pragma unroll
    for (int nf = 0; nf < 2; ++nf) {
      float bv = P.bp[ccol0 + nf*16];
      #pragma unroll
      for (int mf = 0; mf < 2; ++mf)
        #pragma unroll
        for (int jx = 0; jx < 4; ++jx)
          P.out[(size_t)(crow0 + mf*16 + jx)*1024 + ccol0 + nf*16] = acc[mf][nf][jx] + bv;
    }
  }
  grid.sync();

  // ================= Phase 8: LayerNorm (wave per row, 4 rows per task) =================
  for (int t = bid; t < 1024; t += NB) {
    int wid = tid >> 6, lane = tid & 63;
    int row = t*4 + wid;
    float4 x[4];
    float sum = 0.f, ssq = 0.f;
    #pragma unroll
    for (int p = 0; p < 4; ++p) {
      x[p] = *reinterpret_cast<float4*>(&P.out[(size_t)row*1024 + (p*64 + lane)*4]);
      sum += x[p].x + x[p].y + x[p].z + x[p].w;
      ssq += x[p].x*x[p].x + x[p].y*x[p].y + x[p].z*x[p].z + x[p].w*x[p].w;
    }
    #pragma unroll
    for (int off = 32; off > 0; off >>= 1) {
      sum += __shfl_xor(sum, off);
      ssq += __shfl_xor(ssq, off);
    }
    float mean = sum * (1.f/1024.f);
    float var  = ssq * (1.f/1024.f) - mean*mean;
    float inv  = 1.0f / sqrtf(var + 1e-6f);
    #pragma unroll
    for (int p = 0; p < 4; ++p) {
      float4 gv = *reinterpret_cast<const float4*>(&P.gamma[(p*64 + lane)*4]);
      float4 bv = *reinterpret_cast<const float4*>(&P.beta[(p*64 + lane)*4]);
      float4 y;
      y.x = (x[p].x - mean)*inv*gv.x + bv.x;
      y.y = (x[p].y - mean)*inv*gv.y + bv.y;
      y.z = (x[p].z - mean)*inv*gv.z + bv.z;
      y.w = (x[p].w - mean)*inv*gv.w + bv.w;
      *reinterpret_cast<float4*>(&P.out[(size_t)row*1024 + (p*64 + lane)*4]) = y;
    }
  }
}

extern "C" void kernel_launch(void* const* d_in, const int* in_sizes, int n_in,
                              void* d_out, int out_size, void* d_ws, size_t ws_size,
                              hipStream_t stream)
{
  Params prm;
  prm.k   = (const float*)d_in[0];
  prm.q   = (const float*)d_in[1];
  prm.v   = (const float*)d_in[2];
  prm.Wq  = (const float*)d_in[3];
  prm.bq  = (const float*)d_in[4];
  prm.Wk  = (const float*)d_in[5];
  prm.Wv  = (const float*)d_in[6];
  prm.Wp  = (const float*)d_in[7];
  prm.bp  = (const float*)d_in[8];
  prm.aw  = (const float*)d_in[9];
  prm.gamma = (const float*)d_in[10];
  prm.beta  = (const float*)d_in[11];
  prm.out = (float*)d_out;

  float* ws = (float*)d_ws;
  prm.uq    = ws;                    // 16384
  prm.uk    = prm.uq + 16384;        // 16384
  prm.cq    = prm.uk + 16384;        // 16
  prm.sq    = prm.cq + 16;           // 65536
  prm.sk    = prm.sq + 65536;        // 65536
  prm.nodes = prm.sk + 65536;        // 1024
  prm.Wn    = prm.nodes + 1024;      // 1024
  const size_t MEG = 1048576;
  f16* f16b = (f16*)(ws + 165904);
  prm.WvTh = f16b;                   // 1M f16
  prm.vTh  = f16b + 1*MEG;           // 4M
  prm.wh   = f16b + 5*MEG;           // 1M
  prm.Ph   = f16b + 6*MEG;           // 1M
  prm.csh  = f16b + 7*MEG;           // 1M
  prm.csl  = f16b + 8*MEG;           // 1M
  prm.Hsh  = f16b + 9*MEG;           // 1M
  prm.Hsl  = f16b + 10*MEG;          // 1M

  int occ = 0;
  hipOccupancyMaxActiveBlocksPerMultiprocessor(&occ,
      reinterpret_cast<const void*>(mega_kernel), 256, 0);
  if (occ < 1) occ = 1;
  int NB = occ * 256;                // 256 CUs on MI355X
  if (NB > 1024) NB = 1024;
  prm.NB = NB;

  void* args[] = { &prm };
  hipLaunchCooperativeKernel(reinterpret_cast<void*>(mega_kernel),
                             dim3(NB), dim3(256), args, 0, stream);
}

// Round 9
// 183.185 us; speedup vs baseline: 3.3465x; 3.3465x over previous
//
#include <hip/hip_runtime.h>
#include <math.h>

#define SEQ   1024
#define EMB   1024
#define MN    16

typedef _Float16 f16;
typedef __attribute__((ext_vector_type(4))) _Float16 f16x4;
typedef __attribute__((ext_vector_type(8))) _Float16 f16x8;
typedef __attribute__((ext_vector_type(4))) float f32x4;

// ---------- prep: blocks 0..127 fold | 128..1407 ztrans(v,Wv) | 1408 cq | 1409 Wn zero ----------
__global__ __launch_bounds__(256) void prep_kernel(
    const float* __restrict__ Wq, const float* __restrict__ Wk,
    const float* __restrict__ bq, const float* __restrict__ aw,
    const float* __restrict__ v, const float* __restrict__ Wv,
    float* __restrict__ uq, float* __restrict__ uk,
    float* __restrict__ cq, float* __restrict__ Wn,
    f16* __restrict__ vTh, f16* __restrict__ WvTh)
{
  __shared__ float tile[64][65];
  const int t = blockIdx.x, tid = threadIdx.x;
  if (t < 128) {
    int idx = t*256 + tid;
    bool isQ = idx < 16384;
    int li = isQ ? idx : idx - 16384;          // li = e*16 + n
    int e = li >> 4, n = li & 15;
    const float* W = isQ ? Wq : Wk;
    const float* w = isQ ? aw : aw + 64;
    const float* wp = &W[(size_t)e*EMB + n*64];
    float s = 0.f;
    #pragma unroll 16
    for (int d = 0; d < 64; ++d) s = fmaf(wp[d], w[d], s);
    (isQ ? uq : uk)[li] = s;
  } else if (t < 1408) {
    int tt = t - 128;
    int z = tt >> 8;                            // 0..4 (4 v batches + Wv)
    int ty = (tt >> 4) & 15, tx = tt & 15;
    int r0 = ty*64, c0 = tx*64;
    const float* src = (z < 4) ? &v[(size_t)(z*SEQ + r0)*EMB + c0]
                               : &Wv[(size_t)r0*EMB + c0];
    int rr = tid >> 4, c4 = (tid & 15)*4;
    #pragma unroll
    for (int i = 0; i < 4; ++i) {
      int row = rr + i*16;
      float4 wv = *reinterpret_cast<const float4*>(&src[(size_t)row*EMB + c4]);
      tile[row][c4] = wv.x; tile[row][c4+1] = wv.y;
      tile[row][c4+2] = wv.z; tile[row][c4+3] = wv.w;
    }
    __syncthreads();
    #pragma unroll
    for (int i = 0; i < 4; ++i) {
      int cc = rr + i*16;
      f16x4 hh;
      #pragma unroll
      for (int jj = 0; jj < 4; ++jj) hh[jj] = (f16)tile[c4+jj][cc];
      size_t o = (z < 4) ? ((size_t)(z*EMB + c0 + cc))*SEQ + r0 + c4
                         : ((size_t)(c0 + cc))*EMB + r0 + c4;
      *reinterpret_cast<f16x4*>(&((z < 4) ? vTh : WvTh)[o]) = hh;
    }
  } else if (t == 1408) {
    if (tid < 16) {
      float s = 0.f;
      for (int d = 0; d < 64; ++d) s = fmaf(bq[tid*64+d], aw[d], s);
      cq[tid] = s;
    }
  } else {
    for (int u = tid; u < 1024; u += 256) Wn[u] = 0.f;
  }
}

// ---------- sqsk: 8 rows per block ----------
__global__ __launch_bounds__(256) void sqsk2_kernel(
    const float* __restrict__ q, const float* __restrict__ k,
    const float* __restrict__ uq, const float* __restrict__ uk,
    const float* __restrict__ cq, float* __restrict__ sq, float* __restrict__ sk)
{
  __shared__ float rowbuf[8][EMB];
  __shared__ float part[16][8][17];
  int bid = blockIdx.x;
  bool isQ = bid < 512;
  int row0 = (isQ ? bid : bid - 512)*8;
  const float* X = isQ ? q : k;
  const float* U = isQ ? uq : uk;
  int tid = threadIdx.x;
  #pragma unroll
  for (int p = 0; p < 8; ++p) {
    int fi = p*256 + tid;
    int r = fi >> 8, c4 = (fi & 255)*4;
    *reinterpret_cast<float4*>(&rowbuf[r][c4]) =
        *reinterpret_cast<const float4*>(&X[(size_t)(row0+r)*EMB + c4]);
  }
  __syncthreads();
  int n = tid & 15, ch = tid >> 4;
  float acc[8] = {0,0,0,0,0,0,0,0};
  #pragma unroll 4
  for (int e0 = 0; e0 < 64; ++e0) {
    int e = ch*64 + e0;
    float u = U[e*16 + n];
    #pragma unroll
    for (int r = 0; r < 8; ++r) acc[r] = fmaf(rowbuf[r][e], u, acc[r]);
  }
  #pragma unroll
  for (int r = 0; r < 8; ++r) part[ch][r][n] = acc[r];
  __syncthreads();
  if (tid < 128) {
    int r = tid >> 4, nn = tid & 15;
    float s = isQ ? cq[nn] : 0.f;
    #pragma unroll
    for (int c = 0; c < 16; ++c) s += part[c][r][nn];
    (isQ ? sq : sk)[(size_t)(row0+r)*16 + nn] = s;
  }
}

// ---------- wmatn: per-(qd,n,b) block; nodes recomputed in-block (qd==0 writes them);
//            w = exp(tanh(node+sk)) -> wh ; Wn row-sums via atomics ----------
__global__ __launch_bounds__(256) void wmatn_kernel(
    const float* __restrict__ sq, const float* __restrict__ sk,
    f16* __restrict__ wh, float* __restrict__ nodes, float* __restrict__ Wn)
{
  __shared__ float smn[256], smx[256];
  __shared__ float nodesh[MN], Wnl[MN];
  const int qd = blockIdx.x, n = blockIdx.y, b = blockIdx.z;
  const int tid = threadIdx.x;
  // min/max of sq[b,:,n]
  float mn = 1e30f, mx = -1e30f;
  #pragma unroll
  for (int s = 0; s < 4; ++s) {
    float vv = sq[((size_t)(b*SEQ + tid + s*256))*16 + n];
    mn = fminf(mn, vv); mx = fmaxf(mx, vv);
  }
  smn[tid] = mn; smx[tid] = mx;
  __syncthreads();
  for (int off = 128; off > 0; off >>= 1) {
    if (tid < off) { smn[tid] = fminf(smn[tid], smn[tid+off]);
                     smx[tid] = fmaxf(smx[tid], smx[tid+off]); }
    __syncthreads();
  }
  if (tid < MN) {
    float c = 0.5f*(smn[0]+smx[0]);
    float r = fmaxf(0.5f*(smx[0]-smn[0]), 1e-4f);
    float nv = c + r*cosf(tid*(3.14159265358979323f/(MN-1)));
    nodesh[tid] = nv;
    Wnl[tid] = 0.f;
    if (qd == 0) nodes[(b*16+n)*MN + tid] = nv;   // deterministic across qd
  }
  __syncthreads();
  const int j = qd*256 + tid;
  const float skv = sk[((size_t)(b*SEQ + j))*16 + n];
  const int lane = tid & 63;
  #pragma unroll 4
  for (int m = 0; m < MN; ++m) {
    float s = nodesh[m] + skv;
    float e2 = __expf(2.f*s);
    float th = 1.f - 2.f/(e2+1.f);
    float w = __expf(th);
    wh[(size_t)(b*256 + n*MN + m)*1024 + j] = (f16)w;
    float ws = w;
    #pragma unroll
    for (int off = 32; off > 0; off >>= 1) ws += __shfl_xor(ws, off);
    if (lane == 0) atomicAdd(&Wnl[m], ws);
  }
  __syncthreads();
  if (tid < MN) atomicAdd(&Wn[(b*16+n)*MN + tid], Wnl[tid]);
}

// ---------- g1c: blocks 0..255 gemm1 (P = wh @ vT^T', 64x64, K=1024, plain f16)
//                 blocks 256..511 coeff (cs = 1024*barycentric, f16 split) ----------
__global__ __launch_bounds__(256) void g1c_kernel(
    const f16* __restrict__ wh, const f16* __restrict__ vTh,
    f16* __restrict__ Ph,
    const float* __restrict__ sq, const float* __restrict__ nodes,
    const float* __restrict__ Wn, f16* __restrict__ csh, f16* __restrict__ csl)
{
  __shared__ __align__(16) char SMEM[16384];
  const int t = blockIdx.x, tid = threadIdx.x;
  if (t < 256) {
    int swz = (t & 7)*32 + (t >> 3);            // bijective XCD swizzle
    int bx = swz & 15, by = swz >> 4;
    int z = by >> 2;
    int grow = by*64, bcol = bx*64;
    int wid = tid >> 6, lane = tid & 63;
    int wm = wid >> 1, wn = wid & 1;
    int asel = lane >> 4, l15 = lane & 15;
    const f16* Bz = vTh + (size_t)z*EMB*SEQ;
    char* lds = SMEM;
    f32x4 acc[2][2];
    #pragma unroll
    for (int i = 0; i < 2; ++i)
      #pragma unroll
      for (int jx = 0; jx < 2; ++jx)
        acc[i][jx] = (f32x4){0.f,0.f,0.f,0.f};
    for (int kt = 0; kt < 16; ++kt) {
      const int k0 = kt*64;
      __syncthreads();
      #pragma unroll
      for (int r = 0; r < 4; ++r) {
        int ci = ((r & 1) << 8) + tid;
        int row = ci >> 3, kc = ci & 7;
        int kcg = kc ^ (row & 7);
        const f16* base = (r < 2) ? wh : Bz;
        size_t roff = (r < 2) ? (size_t)(grow + row) : (size_t)(bcol + row);
        const char* src = (const char*)(base + roff*1024 + k0 + kcg*8);
        char* dst = lds + (r*256 + wid*64)*16;
        __builtin_amdgcn_global_load_lds(
            (const __attribute__((address_space(1))) unsigned int*)src,
            (__attribute__((address_space(3))) unsigned int*)dst, 16, 0, 0);
      }
      __syncthreads();
      #pragma unroll
      for (int kk = 0; kk < 2; ++kk) {
        f16x8 afh[2], bfh[2];
        #pragma unroll
        for (int mf = 0; mf < 2; ++mf) {
          int row = wm*32 + mf*16 + l15;
          int kcx = (kk*4 + asel) ^ (row & 7);
          afh[mf] = *reinterpret_cast<const f16x8*>(lds + row*128 + kcx*16);
        }
        #pragma unroll
        for (int nf = 0; nf < 2; ++nf) {
          int col = wn*32 + nf*16 + l15;
          int kcx = (kk*4 + asel) ^ (col & 7);
          bfh[nf] = *reinterpret_cast<const f16x8*>(lds + 8192 + col*128 + kcx*16);
        }
        #pragma unroll
        for (int mf = 0; mf < 2; ++mf)
          #pragma unroll
          for (int nf = 0; nf < 2; ++nf)
            acc[mf][nf] = __builtin_amdgcn_mfma_f32_16x16x32_f16(afh[mf], bfh[nf], acc[mf][nf], 0, 0, 0);
      }
    }
    const int crow0 = grow + wm*32 + asel*4;
    const int ccol0 = bcol + wn*32 + l15;
    #pragma unroll
    for (int nf = 0; nf < 2; ++nf)
      #pragma unroll
      for (int mf = 0; mf < 2; ++mf)
        #pragma unroll
        for (int jx = 0; jx < 4; ++jx)
          Ph[(size_t)(crow0 + mf*16 + jx)*1024 + ccol0 + nf*16] = (f16)acc[mf][nf][jx];
  } else {
    int tc = t - 256;
    int ic = tc & 63, b = tc >> 6;
    float (*nsh)[MN] = (float(*)[MN])SMEM;
    float (*wsh)[MN] = ((float(*)[MN])SMEM) + 16;
    {
      int nn = tid >> 4, mm = tid & 15;
      nsh[nn][mm] = nodes[(b*16+nn)*MN + mm];
      wsh[nn][mm] = Wn[(b*16+nn)*MN + mm];
    }
    __syncthreads();
    int il = tid >> 4, n = tid & 15;
    int i = ic*16 + il;
    float s = sq[((size_t)(b*SEQ + i))*16 + n];
    float lam[MN];
    float den = 0.f;
    int ex = -1;
    #pragma unroll
    for (int m = 0; m < MN; ++m) {
      float diff = s - nsh[n][m];
      float wb = ((m == 0) | (m == MN-1)) ? 0.5f : 1.0f;
      wb = (m & 1) ? -wb : wb;
      if (diff == 0.f) ex = m;
      lam[m] = wb / diff;
      den = fmaf(lam[m], wsh[n][m], den);
    }
    float rden = 1024.f / den;
    f16* hp = &csh[((size_t)(b*SEQ + i))*256 + n*MN];
    f16* lp = &csl[((size_t)(b*SEQ + i))*256 + n*MN];
    #pragma unroll
    for (int m8 = 0; m8 < 2; ++m8) {
      f16x8 hv, lv;
      #pragma unroll
      for (int jj = 0; jj < 8; ++jj) {
        int m = m8*8 + jj;
        float c = (ex >= 0) ? ((m == ex) ? 1024.f/wsh[n][ex] : 0.f) : lam[m]*rden;
        f16 h = (f16)c;
        hv[jj] = h; lv[jj] = (f16)(c - (float)h);
      }
      *reinterpret_cast<f16x8*>(&hp[m8*8]) = hv;
      *reinterpret_cast<f16x8*>(&lp[m8*8]) = lv;
    }
  }
}

// ---------- ghprep (fused gfin+hprep): G via MFMA -> Hs = (G@Wp)*2^-10 split ----------
__global__ __launch_bounds__(256) void ghprep_kernel(
    const f16* __restrict__ Ph, const f16* __restrict__ WvTh,
    const float* __restrict__ Wp, f16* __restrict__ Hsh, f16* __restrict__ Hsl)
{
  __shared__ float Gsh[MN][64];
  const int oc = blockIdx.x, n = blockIdx.y, b = blockIdx.z;
  const int bn = b*16 + n;
  const int tid = threadIdx.x;
  const int w = tid >> 6, lane = tid & 63;
  const int l15 = lane & 15, asel = lane >> 4;
  f32x4 acc = (f32x4){0.f,0.f,0.f,0.f};
  #pragma unroll 4
  for (int ks = 0; ks < 32; ++ks) {
    size_t bo = ((size_t)(n*64 + w*16 + l15))*1024 + ks*32 + asel*8;
    f16x8 bh = *reinterpret_cast<const f16x8*>(&WvTh[bo]);
    size_t ao = ((size_t)(bn*MN + l15))*1024 + ks*32 + asel*8;
    f16x8 ah = *reinterpret_cast<const f16x8*>(&Ph[ao]);
    acc = __builtin_amdgcn_mfma_f32_16x16x32_f16(ah, bh, acc, 0, 0, 0);
  }
  #pragma unroll
  for (int jx = 0; jx < 4; ++jx)
    Gsh[asel*4 + jx][w*16 + l15] = acc[jx];
  __syncthreads();
  const int o = oc*256 + tid;
  float a2[MN];
  #pragma unroll
  for (int m = 0; m < MN; ++m) a2[m] = 0.f;
  for (int d = 0; d < 64; ++d) {
    float wp = Wp[(size_t)(n*64 + d)*1024 + o];
    #pragma unroll
    for (int m = 0; m < MN; ++m) a2[m] = fmaf(wp, Gsh[m][d], a2[m]);
  }
  f16 hbuf[MN], lbuf[MN];
  #pragma unroll
  for (int m = 0; m < MN; ++m) {
    float vv = a2[m] * (1.f/1024.f);
    f16 h = (f16)vv;
    hbuf[m] = h; lbuf[m] = (f16)(vv - (float)h);
  }
  size_t base = ((size_t)(b*1024 + o))*256 + n*MN;
  #pragma unroll
  for (int m8 = 0; m8 < 2; ++m8) {
    *reinterpret_cast<f16x8*>(&Hsh[base + m8*8]) = *reinterpret_cast<f16x8*>(&hbuf[m8*8]);
    *reinterpret_cast<f16x8*>(&Hsl[base + m8*8]) = *reinterpret_cast<f16x8*>(&lbuf[m8*8]);
  }
}

// ---------- gemm2: split-3, 128x64 tile, batched; out = cs @ Hs^T' + bp, K=256 ----------
__global__ __launch_bounds__(256) void gemm2_k(
    const f16* __restrict__ Ah, const f16* __restrict__ Al,
    const f16* __restrict__ Bh, const f16* __restrict__ Bl,
    const float* __restrict__ bias, float* __restrict__ Cf)
{
  __shared__ __align__(16) char lds[49152];   // Ah 16K | Al 16K | Bh 8K | Bl 8K
  const int tid = threadIdx.x;
  const int wid = tid >> 6, lane = tid & 63;
  int flat = (blockIdx.z * 8 + blockIdx.y) * 16 + blockIdx.x;
  int swz = (flat & 7) * 64 + (flat >> 3);    // bijective XCD swizzle, 512 blocks
  const int bx = swz & 15;
  const int t2 = swz >> 4;
  const int by = t2 & 7, z = t2 >> 3;
  const int brow = by * 128;
  const int bcol = bx * 64;
  const int wm = wid >> 1, wn = wid & 1;
  const int asel = lane >> 4, l15 = lane & 15;
  const int K = 256, N = 1024, MZ = 1024;
  const f16* Az_h = Ah + (size_t)z*MZ*K;
  const f16* Az_l = Al + (size_t)z*MZ*K;
  const f16* Bz_h = Bh + (size_t)z*N*K;
  const f16* Bz_l = Bl + (size_t)z*N*K;

  f32x4 acc[4][2];
  #pragma unroll
  for (int i = 0; i < 4; ++i)
    #pragma unroll
    for (int jx = 0; jx < 2; ++jx)
      acc[i][jx] = (f32x4){0.f, 0.f, 0.f, 0.f};

  for (int t = 0; t < 4; ++t) {
    const int k0 = t * 64;
    __syncthreads();
    #pragma unroll
    for (int r = 0; r < 12; ++r) {
      const char* src;
      if (r < 8) {
        int ci = ((r & 3) << 8) + tid;
        int row = ci >> 3, kc = ci & 7;
        int kcg = kc ^ (row & 7);
        const f16* base = (r < 4) ? Az_h : Az_l;
        src = (const char*)(base + (size_t)(brow + row) * K + k0 + kcg * 8);
      } else {
        int ci = ((r & 1) << 8) + tid;
        int col = ci >> 3, kc = ci & 7;
        int kcg = kc ^ (col & 7);
        const f16* base = (r < 10) ? Bz_h : Bz_l;
        src = (const char*)(base + (size_t)(bcol + col) * K + k0 + kcg * 8);
      }
      char* dst = lds + (r * 256 + wid * 64) * 16;
      __builtin_amdgcn_global_load_lds(
          (const __attribute__((address_space(1))) unsigned int*)src,
          (__attribute__((address_space(3))) unsigned int*)dst, 16, 0, 0);
    }
    __syncthreads();
    #pragma unroll
    for (int kk = 0; kk < 2; ++kk) {
      f16x8 afh[4], afl[4], bfh[2], bfl[2];
      #pragma unroll
      for (int mf = 0; mf < 4; ++mf) {
        int row = wm * 64 + mf * 16 + l15;
        int kcx = (kk * 4 + asel) ^ (row & 7);
        int off = row * 128 + kcx * 16;
        afh[mf] = *reinterpret_cast<const f16x8*>(lds + off);
        afl[mf] = *reinterpret_cast<const f16x8*>(lds + 16384 + off);
      }
      #pragma unroll
      for (int nf = 0; nf < 2; ++nf) {
        int col = wn * 32 + nf * 16 + l15;
        int kcx = (kk * 4 + asel) ^ (col & 7);
        int off = col * 128 + kcx * 16;
        bfh[nf] = *reinterpret_cast<const f16x8*>(lds + 32768 + off);
        bfl[nf] = *reinterpret_cast<const f16x8*>(lds + 40960 + off);
      }
      #pragma unroll
      for (int mf = 0; mf < 4; ++mf)
        #pragma unroll
        for (int nf = 0; nf < 2; ++nf) {
          acc[mf][nf] = __builtin_amdgcn_mfma_f32_16x16x32_f16(afh[mf], bfh[nf], acc[mf][nf], 0, 0, 0);
          acc[mf][nf] = __builtin_amdgcn_mfma_f32_16x16x32_f16(afh[mf], bfl[nf], acc[mf][nf], 0, 0, 0);
          acc[mf][nf] = __builtin_amdgcn_mfma_f32_16x16x32_f16(afl[mf], bfh[nf], acc[mf][nf], 0, 0, 0);
        }
    }
  }
  const int crow0 = z*MZ + brow + wm * 64 + asel * 4;
  const int ccol0 = bcol + wn * 32 + l15;
  #pragma unroll
  for (int nf = 0; nf < 2; ++nf) {
    float bv = bias[ccol0 + nf * 16];
    #pragma unroll
    for (int mf = 0; mf < 4; ++mf)
      #pragma unroll
      for (int jx = 0; jx < 4; ++jx)
        Cf[(size_t)(crow0 + mf*16 + jx) * N + ccol0 + nf*16] = acc[mf][nf][jx] + bv;
  }
}

// ---------- LayerNorm: 1024 blocks, wave per row, 4 rows per block ----------
__global__ __launch_bounds__(256) void ln_kernel(
    float* __restrict__ out, const float* __restrict__ gamma,
    const float* __restrict__ beta)
{
  const int t = blockIdx.x, tid = threadIdx.x;
  int wid = tid >> 6, lane = tid & 63;
  int row = t*4 + wid;
  float4 x[4];
  float sum = 0.f, ssq = 0.f;
  #pragma unroll
  for (int p = 0; p < 4; ++p) {
    x[p] = *reinterpret_cast<float4*>(&out[(size_t)row*1024 + (p*64 + lane)*4]);
    sum += x[p].x + x[p].y + x[p].z + x[p].w;
    ssq += x[p].x*x[p].x + x[p].y*x[p].y + x[p].z*x[p].z + x[p].w*x[p].w;
  }
  #pragma unroll
  for (int off = 32; off > 0; off >>= 1) {
    sum += __shfl_xor(sum, off);
    ssq += __shfl_xor(ssq, off);
  }
  float mean = sum * (1.f/1024.f);
  float var  = ssq * (1.f/1024.f) - mean*mean;
  float inv  = 1.0f / sqrtf(var + 1e-6f);
  #pragma unroll
  for (int p = 0; p < 4; ++p) {
    float4 gv = *reinterpret_cast<const float4*>(&gamma[(p*64 + lane)*4]);
    float4 bv = *reinterpret_cast<const float4*>(&beta[(p*64 + lane)*4]);
    float4 y;
    y.x = (x[p].x - mean)*inv*gv.x + bv.x;
    y.y = (x[p].y - mean)*inv*gv.y + bv.y;
    y.z = (x[p].z - mean)*inv*gv.z + bv.z;
    y.w = (x[p].w - mean)*inv*gv.w + bv.w;
    *reinterpret_cast<float4*>(&out[(size_t)row*1024 + (p*64 + lane)*4]) = y;
  }
}

extern "C" void kernel_launch(void* const* d_in, const int* in_sizes, int n_in,
                              void* d_out, int out_size, void* d_ws, size_t ws_size,
                              hipStream_t stream)
{
  const float* k   = (const float*)d_in[0];
  const float* q   = (const float*)d_in[1];
  const float* v   = (const float*)d_in[2];
  const float* Wq  = (const float*)d_in[3];
  const float* bq  = (const float*)d_in[4];
  const float* Wk  = (const float*)d_in[5];
  const float* Wv  = (const float*)d_in[6];
  const float* Wp  = (const float*)d_in[7];
  const float* bp  = (const float*)d_in[8];
  const float* aw  = (const float*)d_in[9];
  const float* gamma = (const float*)d_in[10];
  const float* beta  = (const float*)d_in[11];
  float* out = (float*)d_out;

  float* ws    = (float*)d_ws;
  float* uq    = ws;                    // 16384
  float* uk    = uq + 16384;            // 16384
  float* cq    = uk + 16384;            // 16
  float* sq    = cq + 16;               // 65536
  float* sk    = sq + 65536;            // 65536
  float* nodes = sk + 65536;            // 1024
  float* Wn    = nodes + 1024;          // 1024
  const size_t MEG = 1048576;
  f16* f16b = (f16*)(ws + 165904);
  f16* WvTh = f16b;                     // 1M f16
  f16* vTh  = f16b + 1*MEG;             // 4M
  f16* wh   = f16b + 5*MEG;             // 1M (1024x1024)
  f16* Ph   = f16b + 6*MEG;             // 1M (1024x1024)
  f16* csh  = f16b + 7*MEG;             // 1M (4096x256)
  f16* csl  = f16b + 8*MEG;             // 1M
  f16* Hsh  = f16b + 9*MEG;             // 1M (4096x256)
  f16* Hsl  = f16b + 10*MEG;            // 1M

  // 1. prep: fold + v/Wv transpose-to-f16 + cq + Wn zero
  prep_kernel<<<1410, 256, 0, stream>>>(Wq, Wk, bq, aw, v, Wv,
                                        uq, uk, cq, Wn, vTh, WvTh);
  // 2. sq / sk
  sqsk2_kernel<<<1024, 256, 0, stream>>>(q, k, uq, uk, cq, sq, sk);
  // 3. wmat with in-block nodes (writes nodes from qd==0) + Wn sums
  wmatn_kernel<<<dim3(4,16,4), 256, 0, stream>>>(sq, sk, wh, nodes, Wn);
  // 4. gemm1 (P = wh @ vT) || coeff (cs)
  g1c_kernel<<<512, 256, 0, stream>>>(wh, vTh, Ph, sq, nodes, Wn, csh, csl);
  // 5. fused G + Hs
  ghprep_kernel<<<dim3(4,16,4), 256, 0, stream>>>(Ph, WvTh, Wp, Hsh, Hsl);
  // 6. out = cs @ Hs^T' + bp  (split-3, K=256)
  gemm2_k<<<dim3(16,8,4), 256, 0, stream>>>(csh, csl, Hsh, Hsl, bp, out);
  // 7. LayerNorm in-place
  ln_kernel<<<1024, 256, 0, stream>>>(out, gamma, beta);
}